// Round 14
// baseline (90.767 us; speedup 1.0000x reference)
//
#include <hip/hip_runtime.h>

typedef short bf16x8 __attribute__((ext_vector_type(8)));
typedef short s16x4 __attribute__((ext_vector_type(4)));
typedef float f32x4 __attribute__((ext_vector_type(4)));
typedef unsigned int uint4v __attribute__((ext_vector_type(4)));
typedef unsigned int uint2v __attribute__((ext_vector_type(2)));

#define BLM   8192   // B*L rows
#define EMB   512
#define LSEQ  2048
#define NHEAD 8
#define HDIM  64

typedef __attribute__((address_space(3))) char lds_ch;
typedef __attribute__((address_space(3))) float lds_f32;

// round-to-nearest-even fp32 -> bf16 (scalar, epilogues)
__device__ __forceinline__ unsigned short f2bf(float x) {
    unsigned int u = __builtin_bit_cast(unsigned int, x);
    u += 0x7FFFu + ((u >> 16) & 1u);
    return (unsigned short)(u >> 16);
}

// packed RNE fp32x2 -> bf16x2 (1 inst)
__device__ __forceinline__ unsigned int cvtpk(float lo, float hi) {
    unsigned int r;
    asm("v_cvt_pk_bf16_f32 %0, %1, %2" : "=v"(r) : "v"(lo), "v"(hi));
    return r;
}

// XOR swizzle for LDS tiles with 128-byte rows (64 bf16).
__device__ __forceinline__ int swz(int row, int bcol) {
    return row * 128 + (bcol ^ ((row & 7) << 4));
}

// async global->LDS, 16B per lane; LDS dest = wave-uniform base + lane*16
#define GLL16(g, l) __builtin_amdgcn_global_load_lds( \
    (const __attribute__((address_space(1))) void*)(g), \
    (__attribute__((address_space(3))) void*)(l), 16, 0, 0)

// hardware transpose read: 4 x bf16 gathered at +0,+32,+64,+96 bytes from addr
#define TR16(dst, a, OFF) asm volatile("ds_read_b64_tr_b16 %0, %1 offset:%2" \
    : "=v"(dst) : "v"(a), "n"(OFF))

// ---------------------------------------------------------------------------
// W fp32 -> bf16 (RNE, identical rounding to the old inline cvt)
// ---------------------------------------------------------------------------
__global__ __launch_bounds__(256) void k_wcvt(
    const float* __restrict__ W, unsigned short* __restrict__ Wb)
{
    int i = (blockIdx.x * 256 + threadIdx.x) * 8;
    float4 a = *(const float4*)(W + i);
    float4 b = *(const float4*)(W + i + 4);
    uint4v p;
    p.x = cvtpk(a.x, a.y); p.y = cvtpk(a.z, a.w);
    p.z = cvtpk(b.x, b.y); p.w = cvtpk(b.z, b.w);
    *(uint4v*)(Wb + i) = p;
}

// ---------------------------------------------------------------------------
// QKV projection (R12 structure, passing): tile 128x128, BK=64, 32KB LDS,
// launch_bounds(256,3), T14 reg prefetch. ONLY change vs R12: B comes from
// pre-converted bf16 weights and is staged with the uint4v reg->LDS path
// proven in k_gemm_out's A staging since R2 (identical chunk formulas).
// z==0 (Q) epilogue folds 0.125*log2(e) for the max-free softmax downstream.
// ---------------------------------------------------------------------------
__global__ __launch_bounds__(256, 3) void k_gemm_qkv(
    const float* __restrict__ Xq, const float* __restrict__ Xk, const float* __restrict__ Xv,
    const unsigned short* __restrict__ Wqb, const unsigned short* __restrict__ Wkb,
    const unsigned short* __restrict__ Wvb,
    const float* __restrict__ bq, const float* __restrict__ bk, const float* __restrict__ bv,
    unsigned short* __restrict__ Qb, unsigned short* __restrict__ Kb, unsigned short* __restrict__ Vb)
{
    const int z = blockIdx.z;
    const float* X = (z == 0) ? Xq : (z == 1) ? Xk : Xv;
    const unsigned short* Wb = (z == 0) ? Wqb : (z == 1) ? Wkb : Wvb;
    const float* bias = (z == 0) ? bq : (z == 1) ? bk : bv;
    unsigned short* out = (z == 0) ? Qb : (z == 1) ? Kb : Vb;
    const float osc = (z == 0) ? 0.125f * 1.44269504088896340736f : 1.0f;

    __shared__ __align__(16) char lds[32768];
    char* As = lds;
    char* Bs = lds + 16384;

    const int tid  = threadIdx.x;
    const int lane = tid & 63;
    const int wave = tid >> 6;
    const int wm = wave >> 1, wn = wave & 1;
    const int lr = lane & 15, lk = lane >> 4;
    const int m0 = blockIdx.x * 128, n0 = blockIdx.y * 128;

    f32x4 acc[4][4] = {};

    // A prefetch (fp32): chunk i covers row (tid>>4)+16*i, float4-col tid&15
    const float* pa = X + (size_t)(m0 + (tid >> 4)) * EMB + (tid & 15) * 4;
    // B prefetch (bf16): chunk i covers row (tid>>3)+32*i, 8-elem col tid&7
    const unsigned short* pB = Wb + (size_t)(n0 + (tid >> 3)) * EMB + (tid & 7) * 8;

    float4 ar[8]; uint4v brB[4];
    #pragma unroll
    for (int i = 0; i < 8; ++i)
        ar[i] = *(const float4*)(pa + (size_t)i * 16 * EMB);
    #pragma unroll
    for (int i = 0; i < 4; ++i)
        brB[i] = *(const uint4v*)(pB + (size_t)i * 32 * EMB);
    pa += 64; pB += 64;

    for (int kt = 0; kt < 8; ++kt) {
        __syncthreads();                 // previous compute done -> LDS free
        #pragma unroll
        for (int i = 0; i < 8; ++i) {
            int f = tid + i * 256;
            int r = f >> 4, c4 = f & 15;
            uint2v p; p.x = cvtpk(ar[i].x, ar[i].y); p.y = cvtpk(ar[i].z, ar[i].w);
            *(uint2v*)(As + swz(r, c4 * 8)) = p;
        }
        #pragma unroll
        for (int i = 0; i < 4; ++i) {
            int f = tid + i * 256;
            int r = f >> 3, c8 = f & 7;
            *(uint4v*)(Bs + swz(r, c8 * 16)) = brB[i];
        }
        if (kt < 7) {                    // T14: next tile loads in flight
            #pragma unroll
            for (int i = 0; i < 8; ++i)
                ar[i] = *(const float4*)(pa + (size_t)i * 16 * EMB);
            #pragma unroll
            for (int i = 0; i < 4; ++i)
                brB[i] = *(const uint4v*)(pB + (size_t)i * 32 * EMB);
            pa += 64; pB += 64;
        }
        __syncthreads();                 // LDS tile ready
        #pragma unroll
        for (int ks = 0; ks < 2; ++ks) {
            bf16x8 af[4], bfr[4];
            #pragma unroll
            for (int fm = 0; fm < 4; ++fm)
                af[fm] = *(const bf16x8*)(As + swz(wm * 64 + fm * 16 + lr, ks * 64 + lk * 16));
            #pragma unroll
            for (int fn = 0; fn < 4; ++fn)
                bfr[fn] = *(const bf16x8*)(Bs + swz(wn * 64 + fn * 16 + lr, ks * 64 + lk * 16));
            #pragma unroll
            for (int fm = 0; fm < 4; ++fm)
                #pragma unroll
                for (int fn = 0; fn < 4; ++fn)
                    acc[fm][fn] = __builtin_amdgcn_mfma_f32_16x16x32_bf16(af[fm], bfr[fn], acc[fm][fn], 0, 0, 0);
        }
    }
    #pragma unroll
    for (int fn = 0; fn < 4; ++fn) {
        int n = n0 + wn * 64 + fn * 16 + lr;
        float bv_ = bias[n];
        #pragma unroll
        for (int fm = 0; fm < 4; ++fm) {
            int mb = m0 + wm * 64 + fm * 16 + lk * 4;
            #pragma unroll
            for (int j = 0; j < 4; ++j)
                out[(size_t)(mb + j) * EMB + n] = f2bf((acc[fm][fn][j] + bv_) * osc);
        }
    }
}

// ---------------------------------------------------------------------------
// Fused output projection + bias + residual + LayerNorm (R11 version: B dbuf,
// 137KB LDS, 1 block/CU — measured best).
// ---------------------------------------------------------------------------
__global__ __launch_bounds__(256) void k_gemm_out_ln(
    const unsigned short* __restrict__ AO, const unsigned short* __restrict__ Wob,
    const float* __restrict__ bo, const float* __restrict__ res,
    const float* __restrict__ g, const float* __restrict__ bta,
    float* __restrict__ out)
{
    __shared__ __align__(16) char lds[140288];  // A 2x4KB | B 2x64KB | red 1KB
    lds_ch* LA   = (lds_ch*)lds;
    lds_ch* LBUF = (lds_ch*)lds + 8192;
    lds_f32* red = (lds_f32*)((lds_ch*)lds + 139264);

    const int tid  = threadIdx.x;
    const int lane = tid & 63;
    const int wave = tid >> 6;
    const int lr = lane & 15, lk = lane >> 4;

    const int orig = (blockIdx.x & 7) * 32 + (blockIdx.x >> 3);
    const int m0 = orig * 32;

    auto kcol = [](int c) { int r = c >> 3; return ((c & 7) * 8) ^ ((r & 7) * 8); };
    const unsigned short* srcA = AO  + (size_t)(m0 + (tid >> 3)) * EMB + kcol(tid);
    const unsigned short* srcB = Wob + (size_t)(tid >> 3) * EMB + kcol(tid);

    auto stage = [&](int par) {
        lds_ch* ad = LA   + par * 4096  + wave * 1024;
        lds_ch* bd = LBUF + par * 65536 + wave * 1024;
        GLL16(srcA, ad);
        #pragma unroll
        for (int i = 0; i < 16; ++i)
            GLL16(srcB + (size_t)i * 32 * EMB, bd + i * 4096);
        srcA += 64; srcB += 64;
    };

    float bov[8], gv[8], btv[8];
    #pragma unroll
    for (int fn = 0; fn < 8; ++fn) {
        int n = wave * 128 + fn * 16 + lr;
        bov[fn] = bo[n]; gv[fn] = g[n]; btv[fn] = bta[n];
    }

    f32x4 acc[2][8] = {};

    stage(0);

    for (int kt = 0; kt < 8; ++kt) {
        const int par = kt & 1;
        __syncthreads();
        if (kt < 7) stage(par ^ 1);

        char* Asb = (char*)lds + par * 4096;
        char* Bsb = (char*)lds + 8192 + par * 65536;
        #pragma unroll
        for (int ks = 0; ks < 2; ++ks) {
            bf16x8 af[2], bf[8];
            #pragma unroll
            for (int fm = 0; fm < 2; ++fm)
                af[fm] = *(const bf16x8*)(Asb + swz(fm * 16 + lr, ks * 64 + lk * 16));
            #pragma unroll
            for (int fn = 0; fn < 8; ++fn)
                bf[fn] = *(const bf16x8*)(Bsb + swz(wave * 128 + fn * 16 + lr, ks * 64 + lk * 16));
            #pragma unroll
            for (int fm = 0; fm < 2; ++fm)
                #pragma unroll
                for (int fn = 0; fn < 8; ++fn)
                    acc[fm][fn] = __builtin_amdgcn_mfma_f32_16x16x32_bf16(af[fm], bf[fn], acc[fm][fn], 0, 0, 0);
        }
    }

    float ssum[2][4], sqsum[2][4];
    #pragma unroll
    for (int fm = 0; fm < 2; ++fm) {
        #pragma unroll
        for (int j = 0; j < 4; ++j) {
            int rr = fm * 16 + lk * 4 + j;
            const float* rrow = res + (size_t)(m0 + rr) * EMB + wave * 128 + lr;
            float s = 0.f, sq = 0.f;
            #pragma unroll
            for (int fn = 0; fn < 8; ++fn) {
                float x = acc[fm][fn][j] + bov[fn] + rrow[fn * 16];
                acc[fm][fn][j] = x;
                s += x; sq += x * x;
            }
            ssum[fm][j] = s; sqsum[fm][j] = sq;
        }
    }
    #pragma unroll
    for (int fm = 0; fm < 2; ++fm)
        #pragma unroll
        for (int j = 0; j < 4; ++j) {
            float s = ssum[fm][j], sq = sqsum[fm][j];
            #pragma unroll
            for (int msk = 1; msk < 16; msk <<= 1) {
                s  += __shfl_xor(s,  msk);
                sq += __shfl_xor(sq, msk);
            }
            ssum[fm][j] = s; sqsum[fm][j] = sq;
        }
    if (lr == 0) {
        #pragma unroll
        for (int fm = 0; fm < 2; ++fm)
            #pragma unroll
            for (int j = 0; j < 4; ++j) {
                int rr = fm * 16 + lk * 4 + j;
                red[(wave * 32 + rr) * 2 + 0] = ssum[fm][j];
                red[(wave * 32 + rr) * 2 + 1] = sqsum[fm][j];
            }
    }
    __syncthreads();
    #pragma unroll
    for (int fm = 0; fm < 2; ++fm) {
        #pragma unroll
        for (int j = 0; j < 4; ++j) {
            int rr = fm * 16 + lk * 4 + j;
            float tot = 0.f, totsq = 0.f;
            #pragma unroll
            for (int w2 = 0; w2 < 4; ++w2) {
                tot   += red[(w2 * 32 + rr) * 2 + 0];
                totsq += red[(w2 * 32 + rr) * 2 + 1];
            }
            float mu  = tot * (1.f / 512.f);
            float var = totsq * (1.f / 512.f) - mu * mu;
            float rs  = rsqrtf(var + 1e-5f);
            float* orow = out + (size_t)(m0 + rr) * EMB + wave * 128 + lr;
            #pragma unroll
            for (int fn = 0; fn < 8; ++fn)
                orow[fn * 16] = (acc[fm][fn][j] - mu) * rs * gv[fn] + btv[fn];
        }
    }
}

// ---------------------------------------------------------------------------
// Flash attention: swapped-QK^T, max-free softmax, q x kv wave split.
// (R10/R11 passing structure, unchanged.)
// ---------------------------------------------------------------------------
__global__ __launch_bounds__(256, 4) void k_attn(
    const unsigned short* __restrict__ Qb, const unsigned short* __restrict__ Kb,
    const unsigned short* __restrict__ Vb, unsigned short* __restrict__ AO)
{
    __shared__ __align__(16) char lds[32768];   // K0 K1 V0 V1, 8KB each
    lds_ch* LB = (lds_ch*)lds;

    const int tid  = threadIdx.x;
    const int lane = tid & 63;
    const int wave = tid >> 6;          // 0..3
    const int qh   = wave & 1;          // q half
    const int kvh  = wave >> 1;         // kv half
    const int lr = lane & 15, lk = lane >> 4;

    const int bid  = blockIdx.x;
    const int orig = (bid & 7) * 128 + (bid >> 3);
    const int qx = orig & 31, bh = orig >> 5;
    const int b = bh >> 3, h = bh & 7;
    const size_t base = (size_t)b * LSEQ * EMB + h * HDIM;
    const int q0 = qx * 64 + qh * 32;

    const int c0 = tid, c1 = tid + 256;
    auto kcol = [](int c) { int r = c >> 3; return ((c & 7) * 8) ^ ((r & 7) * 8); };
    const unsigned short* srcK0 = Kb + base + (size_t)(c0 >> 3) * EMB + kcol(c0);
    const unsigned short* srcK1 = Kb + base + (size_t)(c1 >> 3) * EMB + kcol(c1);
    auto vsrc = [&](int c) {
        int kv = ((c >> 3) & 15) * 4 + ((c >> 1) & 3);
        int d  = (c >> 7) * 16 + (c & 1) * 8;
        return Vb + base + (size_t)kv * EMB + d;
    };
    const unsigned short* srcV0 = vsrc(c0);
    const unsigned short* srcV1 = vsrc(c1);

    auto stage = [&](int par) {
        lds_ch* kd = LB + par * 8192 + wave * 1024;
        lds_ch* vd = LB + 16384 + par * 8192 + wave * 1024;
        GLL16(srcK0, kd);
        GLL16(srcK1, kd + 4096);
        GLL16(srcV0, vd);
        GLL16(srcV1, vd + 4096);
        srcK0 += 64 * EMB; srcK1 += 64 * EMB;
        srcV0 += 64 * EMB; srcV1 += 64 * EMB;
    };

    bf16x8 qf[2][2];
    #pragma unroll
    for (int qg = 0; qg < 2; ++qg)
        #pragma unroll
        for (int ks = 0; ks < 2; ++ks)
            qf[qg][ks] = *(const bf16x8*)(Qb + base + (size_t)(q0 + qg * 16 + lr) * EMB + ks * 32 + lk * 8);

    f32x4 oaccT[2][4] = {};
    float lrow[2] = {0.f, 0.f};

    lds_ch* vadB = LB + 16384 + kvh * 1024 + lk * 128 + lr * 2;

    stage(0);

    for (int t = 0; t < 32; ++t) {
        const int par = t & 1;
        __syncthreads();
        if (t < 31) stage(par ^ 1);

        char* Kl = lds + par * 8192;
        f32x4 s0[2] = {}, s1[2] = {};
        __builtin_amdgcn_s_setprio(1);
        #pragma unroll
        for (int ks = 0; ks < 2; ++ks) {
            bf16x8 kf0 = *(const bf16x8*)(Kl + swz((kvh * 2 + 0) * 16 + lr, ks * 64 + lk * 16));
            bf16x8 kf1 = *(const bf16x8*)(Kl + swz((kvh * 2 + 1) * 16 + lr, ks * 64 + lk * 16));
            s0[0] = __builtin_amdgcn_mfma_f32_16x16x32_bf16(kf0, qf[0][ks], s0[0], 0, 0, 0);
            s1[0] = __builtin_amdgcn_mfma_f32_16x16x32_bf16(kf0, qf[1][ks], s1[0], 0, 0, 0);
            s0[1] = __builtin_amdgcn_mfma_f32_16x16x32_bf16(kf1, qf[0][ks], s0[1], 0, 0, 0);
            s1[1] = __builtin_amdgcn_mfma_f32_16x16x32_bf16(kf1, qf[1][ks], s1[1], 0, 0, 0);
        }
        __builtin_amdgcn_s_setprio(0);

        #pragma unroll
        for (int blk = 0; blk < 2; ++blk)
            #pragma unroll
            for (int j = 0; j < 4; ++j) {
                s0[blk][j] = __builtin_amdgcn_exp2f(s0[blk][j]);
                s1[blk][j] = __builtin_amdgcn_exp2f(s1[blk][j]);
            }
        {
            f32x4 pc = s0[0] + s0[1];
            lrow[0] += (pc[0] + pc[1]) + (pc[2] + pc[3]);
            f32x4 qc = s1[0] + s1[1];
            lrow[1] += (qc[0] + qc[1]) + (qc[2] + qc[3]);
        }

        uint4v w;
        w.x = cvtpk(s0[0][0], s0[0][1]); w.y = cvtpk(s0[0][2], s0[0][3]);
        w.z = cvtpk(s0[1][0], s0[1][1]); w.w = cvtpk(s0[1][2], s0[1][3]);
        bf16x8 pf0 = __builtin_bit_cast(bf16x8, w);
        uint4v v;
        v.x = cvtpk(s1[0][0], s1[0][1]); v.y = cvtpk(s1[0][2], s1[0][3]);
        v.z = cvtpk(s1[1][0], s1[1][1]); v.w = cvtpk(s1[1][2], s1[1][3]);
        bf16x8 pf1 = __builtin_bit_cast(bf16x8, v);

        lds_ch* vad = vadB + par * 8192;
        uint2v a0, b0, a1, b1, a2, b2, a3, b3;
        __builtin_amdgcn_s_setprio(1);
        TR16(a0, vad, 0);    TR16(b0, vad, 512);
        TR16(a1, vad, 2048); TR16(b1, vad, 2560);
        asm volatile("s_waitcnt lgkmcnt(2)" ::: "memory");
        __builtin_amdgcn_sched_barrier(0);
        {
            uint4v wv; wv.x = a0.x; wv.y = a0.y; wv.z = b0.x; wv.w = b0.y;
            bf16x8 vf = __builtin_bit_cast(bf16x8, wv);
            oaccT[0][0] = __builtin_amdgcn_mfma_f32_16x16x32_bf16(vf, pf0, oaccT[0][0], 0, 0, 0);
            oaccT[1][0] = __builtin_amdgcn_mfma_f32_16x16x32_bf16(vf, pf1, oaccT[1][0], 0, 0, 0);
        }
        TR16(a2, vad, 4096); TR16(b2, vad, 4608);
        asm volatile("s_waitcnt lgkmcnt(2)" ::: "memory");
        __builtin_amdgcn_sched_barrier(0);
        {
            uint4v wv; wv.x = a1.x; wv.y = a1.y; wv.z = b1.x; wv.w = b1.y;
            bf16x8 vf = __builtin_bit_cast(bf16x8, wv);
            oaccT[0][1] = __builtin_amdgcn_mfma_f32_16x16x32_bf16(vf, pf0, oaccT[0][1], 0, 0, 0);
            oaccT[1][1] = __builtin_amdgcn_mfma_f32_16x16x32_bf16(vf, pf1, oaccT[1][1], 0, 0, 0);
        }
        TR16(a3, vad, 6144); TR16(b3, vad, 6656);
        asm volatile("s_waitcnt lgkmcnt(2)" ::: "memory");
        __builtin_amdgcn_sched_barrier(0);
        {
            uint4v wv; wv.x = a2.x; wv.y = a2.y; wv.z = b2.x; wv.w = b2.y;
            bf16x8 vf = __builtin_bit_cast(bf16x8, wv);
            oaccT[0][2] = __builtin_amdgcn_mfma_f32_16x16x32_bf16(vf, pf0, oaccT[0][2], 0, 0, 0);
            oaccT[1][2] = __builtin_amdgcn_mfma_f32_16x16x32_bf16(vf, pf1, oaccT[1][2], 0, 0, 0);
        }
        asm volatile("s_waitcnt lgkmcnt(0)" ::: "memory");
        __builtin_amdgcn_sched_barrier(0);
        {
            uint4v wv; wv.x = a3.x; wv.y = a3.y; wv.z = b3.x; wv.w = b3.y;
            bf16x8 vf = __builtin_bit_cast(bf16x8, wv);
            oaccT[0][3] = __builtin_amdgcn_mfma_f32_16x16x32_bf16(vf, pf0, oaccT[0][3], 0, 0, 0);
            oaccT[1][3] = __builtin_amdgcn_mfma_f32_16x16x32_bf16(vf, pf1, oaccT[1][3], 0, 0, 0);
        }
        __builtin_amdgcn_s_setprio(0);
    }

    __syncthreads();
    lds_f32* red = (lds_f32*)LB;
    if (kvh == 1) {
        lds_f32* dst = red + (qh * 64 + lane) * 34;
        #pragma unroll
        for (int qg = 0; qg < 2; ++qg)
            #pragma unroll
            for (int fd = 0; fd < 4; ++fd)
                #pragma unroll
                for (int j = 0; j < 4; ++j)
                    dst[qg * 16 + fd * 4 + j] = oaccT[qg][fd][j];
        dst[32] = lrow[0]; dst[33] = lrow[1];
    }
    __syncthreads();
    if (kvh == 0) {
        const lds_f32* src = red + (qh * 64 + lane) * 34;
        #pragma unroll
        for (int qg = 0; qg < 2; ++qg)
            #pragma unroll
            for (int fd = 0; fd < 4; ++fd)
                #pragma unroll
                for (int j = 0; j < 4; ++j)
                    oaccT[qg][fd][j] += src[qg * 16 + fd * 4 + j];
        lrow[0] += src[32]; lrow[1] += src[33];

        #pragma unroll
        for (int qg = 0; qg < 2; ++qg) {
            float lr_ = lrow[qg];
            lr_ += __shfl_xor(lr_, 16);
            lr_ += __shfl_xor(lr_, 32);
            float inv = 1.f / lr_;
            unsigned short* aorow = AO + base + (size_t)(q0 + qg * 16 + lr) * EMB;
            #pragma unroll
            for (int fd = 0; fd < 4; ++fd) {
                s16x4 s;
                #pragma unroll
                for (int j = 0; j < 4; ++j) s[j] = (short)f2bf(oaccT[qg][fd][j] * inv);
                *(s16x4*)(aorow + fd * 16 + lk * 4) = s;
            }
        }
    }
}

extern "C" void kernel_launch(void* const* d_in, const int* in_sizes, int n_in,
                              void* d_out, int out_size, void* d_ws, size_t ws_size,
                              hipStream_t stream) {
    const float* values = (const float*)d_in[0];
    const float* keys   = (const float*)d_in[1];
    const float* query  = (const float*)d_in[2];
    const float* Wq = (const float*)d_in[3];  const float* bq = (const float*)d_in[4];
    const float* Wk = (const float*)d_in[5];  const float* bk = (const float*)d_in[6];
    const float* Wv = (const float*)d_in[7];  const float* bv = (const float*)d_in[8];
    const float* Wo = (const float*)d_in[9];  const float* bo = (const float*)d_in[10];
    const float* lng = (const float*)d_in[11];
    const float* lnb = (const float*)d_in[12];

    char* ws = (char*)d_ws;
    unsigned short* Qb = (unsigned short*)(ws);                       //  8 MB bf16
    unsigned short* Kb = (unsigned short*)(ws + 8u  * 1024 * 1024);   //  8 MB
    unsigned short* Vb = (unsigned short*)(ws + 16u * 1024 * 1024);   //  8 MB
    unsigned short* AO = (unsigned short*)(ws + 24u * 1024 * 1024);   //  8 MB
    // bf16 QKV weights live in the AO region until attn overwrites it
    unsigned short* Wqb3 = (unsigned short*)(ws + 24u * 1024 * 1024);
    unsigned short* Wkb3 = Wqb3 + 262144;
    unsigned short* Wvb3 = Wkb3 + 262144;
    unsigned short* Wob  = (unsigned short*)(ws);  // 512 KB; reuses Qb (dead after attn)

    k_wcvt<<<128, 256, 0, stream>>>(Wq, Wqb3);
    k_wcvt<<<128, 256, 0, stream>>>(Wk, Wkb3);
    k_wcvt<<<128, 256, 0, stream>>>(Wv, Wvb3);
    dim3 gqkv(64, 4, 3);
    k_gemm_qkv<<<gqkv, 256, 0, stream>>>(query, keys, values, Wqb3, Wkb3, Wvb3,
                                         bq, bk, bv, Qb, Kb, Vb);
    k_attn<<<1024, 256, 0, stream>>>(Qb, Kb, Vb, AO);
    k_wcvt<<<128, 256, 0, stream>>>(Wo, Wob);
    k_gemm_out_ln<<<256, 256, 0, stream>>>(AO, Wob, bo, query, lng, lnb, (float*)d_out);
}

// Round 16
// 86.384 us; speedup vs baseline: 1.0507x; 1.0507x over previous
//
#include <hip/hip_runtime.h>

typedef short bf16x8 __attribute__((ext_vector_type(8)));
typedef short s16x4 __attribute__((ext_vector_type(4)));
typedef float f32x4 __attribute__((ext_vector_type(4)));
typedef unsigned int uint4v __attribute__((ext_vector_type(4)));
typedef unsigned int uint2v __attribute__((ext_vector_type(2)));

#define BLM   8192   // B*L rows
#define EMB   512
#define LSEQ  2048
#define NHEAD 8
#define HDIM  64

typedef __attribute__((address_space(3))) char lds_ch;
typedef __attribute__((address_space(3))) float lds_f32;

// round-to-nearest-even fp32 -> bf16 (scalar, epilogues)
__device__ __forceinline__ unsigned short f2bf(float x) {
    unsigned int u = __builtin_bit_cast(unsigned int, x);
    u += 0x7FFFu + ((u >> 16) & 1u);
    return (unsigned short)(u >> 16);
}

// packed RNE fp32x2 -> bf16x2 (1 inst)
__device__ __forceinline__ unsigned int cvtpk(float lo, float hi) {
    unsigned int r;
    asm("v_cvt_pk_bf16_f32 %0, %1, %2" : "=v"(r) : "v"(lo), "v"(hi));
    return r;
}

// XOR swizzle for LDS tiles with 128-byte rows (64 bf16).
__device__ __forceinline__ int swz(int row, int bcol) {
    return row * 128 + (bcol ^ ((row & 7) << 4));
}

// async global->LDS, 16B per lane; LDS dest = wave-uniform base + lane*16
#define GLL16(g, l) __builtin_amdgcn_global_load_lds( \
    (const __attribute__((address_space(1))) void*)(g), \
    (__attribute__((address_space(3))) void*)(l), 16, 0, 0)

// hardware transpose read: 4 x bf16 gathered at +0,+32,+64,+96 bytes from addr
#define TR16(dst, a, OFF) asm volatile("ds_read_b64_tr_b16 %0, %1 offset:%2" \
    : "=v"(dst) : "v"(a), "n"(OFF))

// ---------------------------------------------------------------------------
// QKV projection: out[m][n] = sum_k X[m][k] * W[n][k] + bias[n]   (bf16 out)
// z==0 (Q) epilogue folds 0.125*log2(e) -> max-free softmax downstream.
// ---------------------------------------------------------------------------
__global__ __launch_bounds__(256, 3) void k_gemm_qkv(
    const float* __restrict__ Xq, const float* __restrict__ Xk, const float* __restrict__ Xv,
    const float* __restrict__ Wq, const float* __restrict__ Wk, const float* __restrict__ Wv,
    const float* __restrict__ bq, const float* __restrict__ bk, const float* __restrict__ bv,
    unsigned short* __restrict__ Qb, unsigned short* __restrict__ Kb, unsigned short* __restrict__ Vb)
{
    const int z = blockIdx.z;
    const float* X    = (z == 0) ? Xq : (z == 1) ? Xk : Xv;
    const float* W    = (z == 0) ? Wq : (z == 1) ? Wk : Wv;
    const float* bias = (z == 0) ? bq : (z == 1) ? bk : bv;
    unsigned short* out = (z == 0) ? Qb : (z == 1) ? Kb : Vb;
    const float osc = (z == 0) ? 0.125f * 1.44269504088896340736f : 1.0f;

    __shared__ __align__(16) char lds[32768];
    char* As = lds;
    char* Bs = lds + 16384;

    const int tid  = threadIdx.x;
    const int lane = tid & 63;
    const int wave = tid >> 6;
    const int wm = wave >> 1, wn = wave & 1;
    const int lr = lane & 15, lk = lane >> 4;
    const int m0 = blockIdx.x * 128, n0 = blockIdx.y * 128;

    f32x4 acc[4][4] = {};

    const float* pa = X + (size_t)(m0 + (tid >> 4)) * EMB + (tid & 15) * 4;
    const float* pb = W + (size_t)(n0 + (tid >> 4)) * EMB + (tid & 15) * 4;

    float4 ar[8], br[8];
    #pragma unroll
    for (int i = 0; i < 8; ++i) {
        ar[i] = *(const float4*)(pa + (size_t)i * 16 * EMB);
        br[i] = *(const float4*)(pb + (size_t)i * 16 * EMB);
    }
    pa += 64; pb += 64;

    for (int kt = 0; kt < 8; ++kt) {
        __syncthreads();
        #pragma unroll
        for (int i = 0; i < 8; ++i) {
            int f = tid + i * 256;
            int r = f >> 4, c4 = f & 15;
            uint2v p; p.x = cvtpk(ar[i].x, ar[i].y); p.y = cvtpk(ar[i].z, ar[i].w);
            *(uint2v*)(As + swz(r, c4 * 8)) = p;
            uint2v q; q.x = cvtpk(br[i].x, br[i].y); q.y = cvtpk(br[i].z, br[i].w);
            *(uint2v*)(Bs + swz(r, c4 * 8)) = q;
        }
        if (kt < 7) {
            #pragma unroll
            for (int i = 0; i < 8; ++i) {
                ar[i] = *(const float4*)(pa + (size_t)i * 16 * EMB);
                br[i] = *(const float4*)(pb + (size_t)i * 16 * EMB);
            }
            pa += 64; pb += 64;
        }
        __syncthreads();
        #pragma unroll
        for (int ks = 0; ks < 2; ++ks) {
            bf16x8 af[4], bfr[4];
            #pragma unroll
            for (int fm = 0; fm < 4; ++fm)
                af[fm] = *(const bf16x8*)(As + swz(wm * 64 + fm * 16 + lr, ks * 64 + lk * 16));
            #pragma unroll
            for (int fn = 0; fn < 4; ++fn)
                bfr[fn] = *(const bf16x8*)(Bs + swz(wn * 64 + fn * 16 + lr, ks * 64 + lk * 16));
            #pragma unroll
            for (int fm = 0; fm < 4; ++fm)
                #pragma unroll
                for (int fn = 0; fn < 4; ++fn)
                    acc[fm][fn] = __builtin_amdgcn_mfma_f32_16x16x32_bf16(af[fm], bfr[fn], acc[fm][fn], 0, 0, 0);
        }
    }
    #pragma unroll
    for (int fn = 0; fn < 4; ++fn) {
        int n = n0 + wn * 64 + fn * 16 + lr;
        float bv_ = bias[n];
        #pragma unroll
        for (int fm = 0; fm < 4; ++fm) {
            int mb = m0 + wm * 64 + fm * 16 + lk * 4;
            #pragma unroll
            for (int j = 0; j < 4; ++j)
                out[(size_t)(mb + j) * EMB + n] = f2bf((acc[fm][fn][j] + bv_) * osc);
        }
    }
}

// ---------------------------------------------------------------------------
// Wo fp32 -> bf16, once (RNE, same rounding the old per-block cvt produced)
// ---------------------------------------------------------------------------
__global__ __launch_bounds__(256) void k_wcvt(
    const float* __restrict__ W, unsigned short* __restrict__ Wb)
{
    int i = (blockIdx.x * 256 + threadIdx.x) * 8;
    float4 a = *(const float4*)(W + i);
    float4 b = *(const float4*)(W + i + 4);
    uint4v p;
    p.x = cvtpk(a.x, a.y); p.y = cvtpk(a.z, a.w);
    p.z = cvtpk(b.x, b.y); p.w = cvtpk(b.z, b.w);
    *(uint4v*)(Wb + i) = p;
}

// ---------------------------------------------------------------------------
// Fused output projection + bias + residual + LayerNorm.
// Full-row tiles: BM=32, BN=512 (whole row), BK=64. Grid 256 = 1 block/CU,
// 4 waves, wave w owns columns w*128..w*128+127. B (bf16 Wo) and A (AO)
// staged via GLL16 with the validated XOR-swizzle chunk formulas, both
// double-buffered (LDS 137 KB). Epilogue computes X = acc+bo+res in regs,
// then row mean/var: 8-col thread partials -> shfl_xor over lr (4 hops) ->
// 1KB LDS cross-wave reduce -> LN applied -> final fp32 out. Eliminates the
// 64 MB Xr round trip (gemm_out -> k_ln) entirely.
// ---------------------------------------------------------------------------
__global__ __launch_bounds__(256) void k_gemm_out_ln(
    const unsigned short* __restrict__ AO, const unsigned short* __restrict__ Wob,
    const float* __restrict__ bo, const float* __restrict__ res,
    const float* __restrict__ g, const float* __restrict__ bta,
    float* __restrict__ out)
{
    __shared__ __align__(16) char lds[140288];  // A 2x4KB | B 2x64KB | red 1KB
    lds_ch* LA   = (lds_ch*)lds;                // A dbuf at 0
    lds_ch* LBUF = (lds_ch*)lds + 8192;         // B dbuf at 8192
    lds_f32* red = (lds_f32*)((lds_ch*)lds + 139264);

    const int tid  = threadIdx.x;
    const int lane = tid & 63;
    const int wave = tid >> 6;
    const int lr = lane & 15, lk = lane >> 4;

    // XCD swizzle (bijective on [0,256)): each XCD gets contiguous row range
    const int orig = (blockIdx.x & 7) * 32 + (blockIdx.x >> 3);
    const int m0 = orig * 32;

    // ---- staging sources (validated chunk formulas; rows via c>>3, XOR cols)
    auto kcol = [](int c) { int r = c >> 3; return ((c & 7) * 8) ^ ((r & 7) * 8); };
    const unsigned short* srcA = AO  + (size_t)(m0 + (tid >> 3)) * EMB + kcol(tid);
    const unsigned short* srcB = Wob + (size_t)(tid >> 3) * EMB + kcol(tid);
    // B chunk i (i=0..15): row += i*32 (32 = 0 mod 8 -> XOR field invariant)

    auto stage = [&](int par) {
        lds_ch* ad = LA   + par * 4096  + wave * 1024;
        lds_ch* bd = LBUF + par * 65536 + wave * 1024;
        GLL16(srcA, ad);
        #pragma unroll
        for (int i = 0; i < 16; ++i)
            GLL16(srcB + (size_t)i * 32 * EMB, bd + i * 4096);
        srcA += 64; srcB += 64;
    };

    // per-thread column constants: n = wave*128 + fn*16 + lr
    float bov[8], gv[8], btv[8];
    #pragma unroll
    for (int fn = 0; fn < 8; ++fn) {
        int n = wave * 128 + fn * 16 + lr;
        bov[fn] = bo[n]; gv[fn] = g[n]; btv[fn] = bta[n];
    }

    f32x4 acc[2][8] = {};

    stage(0);

    for (int kt = 0; kt < 8; ++kt) {
        const int par = kt & 1;
        __syncthreads();              // drains this step's staging (vmcnt)
        if (kt < 7) stage(par ^ 1);

        char* Asb = (char*)lds + par * 4096;
        char* Bsb = (char*)lds + 8192 + par * 65536;
        #pragma unroll
        for (int ks = 0; ks < 2; ++ks) {
            bf16x8 af[2], bf[8];
            #pragma unroll
            for (int fm = 0; fm < 2; ++fm)
                af[fm] = *(const bf16x8*)(Asb + swz(fm * 16 + lr, ks * 64 + lk * 16));
            #pragma unroll
            for (int fn = 0; fn < 8; ++fn)
                bf[fn] = *(const bf16x8*)(Bsb + swz(wave * 128 + fn * 16 + lr, ks * 64 + lk * 16));
            #pragma unroll
            for (int fm = 0; fm < 2; ++fm)
                #pragma unroll
                for (int fn = 0; fn < 8; ++fn)
                    acc[fm][fn] = __builtin_amdgcn_mfma_f32_16x16x32_bf16(af[fm], bf[fn], acc[fm][fn], 0, 0, 0);
        }
    }

    // ---- epilogue: X = acc + bo + res; row partial sums ----
    float ssum[2][4], sqsum[2][4];
    #pragma unroll
    for (int fm = 0; fm < 2; ++fm) {
        #pragma unroll
        for (int j = 0; j < 4; ++j) {
            int rr = fm * 16 + lk * 4 + j;
            const float* rrow = res + (size_t)(m0 + rr) * EMB + wave * 128 + lr;
            float s = 0.f, sq = 0.f;
            #pragma unroll
            for (int fn = 0; fn < 8; ++fn) {
                float x = acc[fm][fn][j] + bov[fn] + rrow[fn * 16];
                acc[fm][fn][j] = x;
                s += x; sq += x * x;
            }
            ssum[fm][j] = s; sqsum[fm][j] = sq;
        }
    }
    // reduce over the 16 lr lanes (4 hops)
    #pragma unroll
    for (int fm = 0; fm < 2; ++fm)
        #pragma unroll
        for (int j = 0; j < 4; ++j) {
            float s = ssum[fm][j], sq = sqsum[fm][j];
            #pragma unroll
            for (int msk = 1; msk < 16; msk <<= 1) {
                s  += __shfl_xor(s,  msk);
                sq += __shfl_xor(sq, msk);
            }
            ssum[fm][j] = s; sqsum[fm][j] = sq;
        }
    // cross-wave reduce via 1KB LDS region
    if (lr == 0) {
        #pragma unroll
        for (int fm = 0; fm < 2; ++fm)
            #pragma unroll
            for (int j = 0; j < 4; ++j) {
                int rr = fm * 16 + lk * 4 + j;
                red[(wave * 32 + rr) * 2 + 0] = ssum[fm][j];
                red[(wave * 32 + rr) * 2 + 1] = sqsum[fm][j];
            }
    }
    __syncthreads();
    #pragma unroll
    for (int fm = 0; fm < 2; ++fm) {
        #pragma unroll
        for (int j = 0; j < 4; ++j) {
            int rr = fm * 16 + lk * 4 + j;
            float tot = 0.f, totsq = 0.f;
            #pragma unroll
            for (int w2 = 0; w2 < 4; ++w2) {
                tot   += red[(w2 * 32 + rr) * 2 + 0];
                totsq += red[(w2 * 32 + rr) * 2 + 1];
            }
            float mu  = tot * (1.f / 512.f);
            float var = totsq * (1.f / 512.f) - mu * mu;
            float rs  = rsqrtf(var + 1e-5f);
            float* orow = out + (size_t)(m0 + rr) * EMB + wave * 128 + lr;
            #pragma unroll
            for (int fn = 0; fn < 8; ++fn)
                orow[fn * 16] = (acc[fm][fn][j] - mu) * rs * gv[fn] + btv[fn];
        }
    }
}

// ---------------------------------------------------------------------------
// Flash attention: swapped-QK^T, max-free softmax, q x kv wave split.
// (R10 structure, unchanged.)
// ---------------------------------------------------------------------------
__global__ __launch_bounds__(256, 4) void k_attn(
    const unsigned short* __restrict__ Qb, const unsigned short* __restrict__ Kb,
    const unsigned short* __restrict__ Vb, unsigned short* __restrict__ AO)
{
    __shared__ __align__(16) char lds[32768];   // K0 K1 V0 V1, 8KB each
    lds_ch* LB = (lds_ch*)lds;

    const int tid  = threadIdx.x;
    const int lane = tid & 63;
    const int wave = tid >> 6;          // 0..3
    const int qh   = wave & 1;          // q half
    const int kvh  = wave >> 1;         // kv half
    const int lr = lane & 15, lk = lane >> 4;

    const int bid  = blockIdx.x;
    const int orig = (bid & 7) * 128 + (bid >> 3);
    const int qx = orig & 31, bh = orig >> 5;
    const int b = bh >> 3, h = bh & 7;
    const size_t base = (size_t)b * LSEQ * EMB + h * HDIM;
    const int q0 = qx * 64 + qh * 32;

    const int c0 = tid, c1 = tid + 256;
    auto kcol = [](int c) { int r = c >> 3; return ((c & 7) * 8) ^ ((r & 7) * 8); };
    const unsigned short* srcK0 = Kb + base + (size_t)(c0 >> 3) * EMB + kcol(c0);
    const unsigned short* srcK1 = Kb + base + (size_t)(c1 >> 3) * EMB + kcol(c1);
    auto vsrc = [&](int c) {
        int kv = ((c >> 3) & 15) * 4 + ((c >> 1) & 3);
        int d  = (c >> 7) * 16 + (c & 1) * 8;
        return Vb + base + (size_t)kv * EMB + d;
    };
    const unsigned short* srcV0 = vsrc(c0);
    const unsigned short* srcV1 = vsrc(c1);

    auto stage = [&](int par) {
        lds_ch* kd = LB + par * 8192 + wave * 1024;
        lds_ch* vd = LB + 16384 + par * 8192 + wave * 1024;
        GLL16(srcK0, kd);
        GLL16(srcK1, kd + 4096);
        GLL16(srcV0, vd);
        GLL16(srcV1, vd + 4096);
        srcK0 += 64 * EMB; srcK1 += 64 * EMB;
        srcV0 += 64 * EMB; srcV1 += 64 * EMB;
    };

    bf16x8 qf[2][2];
    #pragma unroll
    for (int qg = 0; qg < 2; ++qg)
        #pragma unroll
        for (int ks = 0; ks < 2; ++ks)
            qf[qg][ks] = *(const bf16x8*)(Qb + base + (size_t)(q0 + qg * 16 + lr) * EMB + ks * 32 + lk * 8);

    f32x4 oaccT[2][4] = {};
    float lrow[2] = {0.f, 0.f};

    lds_ch* vadB = LB + 16384 + kvh * 1024 + lk * 128 + lr * 2;

    stage(0);

    for (int t = 0; t < 32; ++t) {
        const int par = t & 1;
        __syncthreads();
        if (t < 31) stage(par ^ 1);

        char* Kl = lds + par * 8192;
        f32x4 s0[2] = {}, s1[2] = {};
        __builtin_amdgcn_s_setprio(1);
        #pragma unroll
        for (int ks = 0; ks < 2; ++ks) {
            bf16x8 kf0 = *(const bf16x8*)(Kl + swz((kvh * 2 + 0) * 16 + lr, ks * 64 + lk * 16));
            bf16x8 kf1 = *(const bf16x8*)(Kl + swz((kvh * 2 + 1) * 16 + lr, ks * 64 + lk * 16));
            s0[0] = __builtin_amdgcn_mfma_f32_16x16x32_bf16(kf0, qf[0][ks], s0[0], 0, 0, 0);
            s1[0] = __builtin_amdgcn_mfma_f32_16x16x32_bf16(kf0, qf[1][ks], s1[0], 0, 0, 0);
            s0[1] = __builtin_amdgcn_mfma_f32_16x16x32_bf16(kf1, qf[0][ks], s0[1], 0, 0, 0);
            s1[1] = __builtin_amdgcn_mfma_f32_16x16x32_bf16(kf1, qf[1][ks], s1[1], 0, 0, 0);
        }
        __builtin_amdgcn_s_setprio(0);

        #pragma unroll
        for (int blk = 0; blk < 2; ++blk)
            #pragma unroll
            for (int j = 0; j < 4; ++j) {
                s0[blk][j] = __builtin_amdgcn_exp2f(s0[blk][j]);
                s1[blk][j] = __builtin_amdgcn_exp2f(s1[blk][j]);
            }
        {
            f32x4 pc = s0[0] + s0[1];
            lrow[0] += (pc[0] + pc[1]) + (pc[2] + pc[3]);
            f32x4 qc = s1[0] + s1[1];
            lrow[1] += (qc[0] + qc[1]) + (qc[2] + qc[3]);
        }

        uint4v w;
        w.x = cvtpk(s0[0][0], s0[0][1]); w.y = cvtpk(s0[0][2], s0[0][3]);
        w.z = cvtpk(s0[1][0], s0[1][1]); w.w = cvtpk(s0[1][2], s0[1][3]);
        bf16x8 pf0 = __builtin_bit_cast(bf16x8, w);
        uint4v v;
        v.x = cvtpk(s1[0][0], s1[0][1]); v.y = cvtpk(s1[0][2], s1[0][3]);
        v.z = cvtpk(s1[1][0], s1[1][1]); v.w = cvtpk(s1[1][2], s1[1][3]);
        bf16x8 pf1 = __builtin_bit_cast(bf16x8, v);

        lds_ch* vad = vadB + par * 8192;
        uint2v a0, b0, a1, b1, a2, b2, a3, b3;
        __builtin_amdgcn_s_setprio(1);
        TR16(a0, vad, 0);    TR16(b0, vad, 512);
        TR16(a1, vad, 2048); TR16(b1, vad, 2560);
        asm volatile("s_waitcnt lgkmcnt(2)" ::: "memory");
        __builtin_amdgcn_sched_barrier(0);
        {
            uint4v wv; wv.x = a0.x; wv.y = a0.y; wv.z = b0.x; wv.w = b0.y;
            bf16x8 vf = __builtin_bit_cast(bf16x8, wv);
            oaccT[0][0] = __builtin_amdgcn_mfma_f32_16x16x32_bf16(vf, pf0, oaccT[0][0], 0, 0, 0);
            oaccT[1][0] = __builtin_amdgcn_mfma_f32_16x16x32_bf16(vf, pf1, oaccT[1][0], 0, 0, 0);
        }
        TR16(a2, vad, 4096); TR16(b2, vad, 4608);
        asm volatile("s_waitcnt lgkmcnt(2)" ::: "memory");
        __builtin_amdgcn_sched_barrier(0);
        {
            uint4v wv; wv.x = a1.x; wv.y = a1.y; wv.z = b1.x; wv.w = b1.y;
            bf16x8 vf = __builtin_bit_cast(bf16x8, wv);
            oaccT[0][1] = __builtin_amdgcn_mfma_f32_16x16x32_bf16(vf, pf0, oaccT[0][1], 0, 0, 0);
            oaccT[1][1] = __builtin_amdgcn_mfma_f32_16x16x32_bf16(vf, pf1, oaccT[1][1], 0, 0, 0);
        }
        TR16(a3, vad, 6144); TR16(b3, vad, 6656);
        asm volatile("s_waitcnt lgkmcnt(2)" ::: "memory");
        __builtin_amdgcn_sched_barrier(0);
        {
            uint4v wv; wv.x = a2.x; wv.y = a2.y; wv.z = b2.x; wv.w = b2.y;
            bf16x8 vf = __builtin_bit_cast(bf16x8, wv);
            oaccT[0][2] = __builtin_amdgcn_mfma_f32_16x16x32_bf16(vf, pf0, oaccT[0][2], 0, 0, 0);
            oaccT[1][2] = __builtin_amdgcn_mfma_f32_16x16x32_bf16(vf, pf1, oaccT[1][2], 0, 0, 0);
        }
        asm volatile("s_waitcnt lgkmcnt(0)" ::: "memory");
        __builtin_amdgcn_sched_barrier(0);
        {
            uint4v wv; wv.x = a3.x; wv.y = a3.y; wv.z = b3.x; wv.w = b3.y;
            bf16x8 vf = __builtin_bit_cast(bf16x8, wv);
            oaccT[0][3] = __builtin_amdgcn_mfma_f32_16x16x32_bf16(vf, pf0, oaccT[0][3], 0, 0, 0);
            oaccT[1][3] = __builtin_amdgcn_mfma_f32_16x16x32_bf16(vf, pf1, oaccT[1][3], 0, 0, 0);
        }
        __builtin_amdgcn_s_setprio(0);
    }

    __syncthreads();
    lds_f32* red = (lds_f32*)LB;
    if (kvh == 1) {
        lds_f32* dst = red + (qh * 64 + lane) * 34;
        #pragma unroll
        for (int qg = 0; qg < 2; ++qg)
            #pragma unroll
            for (int fd = 0; fd < 4; ++fd)
                #pragma unroll
                for (int j = 0; j < 4; ++j)
                    dst[qg * 16 + fd * 4 + j] = oaccT[qg][fd][j];
        dst[32] = lrow[0]; dst[33] = lrow[1];
    }
    __syncthreads();
    if (kvh == 0) {
        const lds_f32* src = red + (qh * 64 + lane) * 34;
        #pragma unroll
        for (int qg = 0; qg < 2; ++qg)
            #pragma unroll
            for (int fd = 0; fd < 4; ++fd)
                #pragma unroll
                for (int j = 0; j < 4; ++j)
                    oaccT[qg][fd][j] += src[qg * 16 + fd * 4 + j];
        lrow[0] += src[32]; lrow[1] += src[33];

        #pragma unroll
        for (int qg = 0; qg < 2; ++qg) {
            float lr_ = lrow[qg];
            lr_ += __shfl_xor(lr_, 16);
            lr_ += __shfl_xor(lr_, 32);
            float inv = 1.f / lr_;
            unsigned short* aorow = AO + base + (size_t)(q0 + qg * 16 + lr) * EMB;
            #pragma unroll
            for (int fd = 0; fd < 4; ++fd) {
                s16x4 s;
                #pragma unroll
                for (int j = 0; j < 4; ++j) s[j] = (short)f2bf(oaccT[qg][fd][j] * inv);
                *(s16x4*)(aorow + fd * 16 + lk * 4) = s;
            }
        }
    }
}

extern "C" void kernel_launch(void* const* d_in, const int* in_sizes, int n_in,
                              void* d_out, int out_size, void* d_ws, size_t ws_size,
                              hipStream_t stream) {
    const float* values = (const float*)d_in[0];
    const float* keys   = (const float*)d_in[1];
    const float* query  = (const float*)d_in[2];
    const float* Wq = (const float*)d_in[3];  const float* bq = (const float*)d_in[4];
    const float* Wk = (const float*)d_in[5];  const float* bk = (const float*)d_in[6];
    const float* Wv = (const float*)d_in[7];  const float* bv = (const float*)d_in[8];
    const float* Wo = (const float*)d_in[9];  const float* bo = (const float*)d_in[10];
    const float* lng = (const float*)d_in[11];
    const float* lnb = (const float*)d_in[12];

    char* ws = (char*)d_ws;
    unsigned short* Qb = (unsigned short*)(ws);                       //  8 MB bf16
    unsigned short* Kb = (unsigned short*)(ws + 8u  * 1024 * 1024);   //  8 MB
    unsigned short* Vb = (unsigned short*)(ws + 16u * 1024 * 1024);   //  8 MB
    unsigned short* AO = (unsigned short*)(ws + 24u * 1024 * 1024);   //  8 MB
    unsigned short* Wob = (unsigned short*)(ws);  // 512 KB; reuses Qb (dead after attn)

    dim3 gqkv(64, 4, 3);
    k_gemm_qkv<<<gqkv, 256, 0, stream>>>(query, keys, values, Wq, Wk, Wv, bq, bk, bv, Qb, Kb, Vb);
    k_attn<<<1024, 256, 0, stream>>>(Qb, Kb, Vb, AO);
    k_wcvt<<<128, 256, 0, stream>>>(Wo, Wob);
    k_gemm_out_ln<<<256, 256, 0, stream>>>(AO, Wob, bo, query, lng, lnb, (float*)d_out);
}